// Round 1
// baseline (836.182 us; speedup 1.0000x reference)
//
#include <hip/hip_runtime.h>

#define B_ 2
#define H_ 16
#define S_ 2048
#define D_ 64
#define QB 32
#define KT 64
#define NTHREADS 512

typedef _Float16 f16;
typedef _Float16 f16x8 __attribute__((ext_vector_type(8)));
typedef _Float16 f16x4 __attribute__((ext_vector_type(4)));
typedef _Float16 f16x2 __attribute__((ext_vector_type(2)));
typedef float f32x4 __attribute__((ext_vector_type(4)));

#define MFMA16(a, b, c) __builtin_amdgcn_mfma_f32_16x16x32_f16(a, b, c, 0, 0, 0)

__global__ __launch_bounds__(NTHREADS)
void attn_kernel(const float* __restrict__ q, const float* __restrict__ k,
                 const float* __restrict__ v, const int* __restrict__ mask,
                 float* __restrict__ out)
{
    // LDS: ~28 KB total -> multiple blocks/CU
    __shared__ f16 Qsh[QB][D_ + 8];    // 32 x 72, row stride 144B (16B-mult, bank-safe)
    __shared__ f16 Ksh[KT][D_ + 8];    // 64 x 72
    __shared__ f16 Vsh[KT][D_ + 2];    // 64 x 66, pad=2 -> conflict-free column reads
    __shared__ f16 Psh[QB][KT + 8];    // 32 x 72
    __shared__ float rowred[QB];
    __shared__ float rlsh[QB];

    const int tid  = threadIdx.x;
    const int wave = tid >> 6;
    const int lane = tid & 63;
    const int quad = lane >> 4;
    const int l16  = lane & 15;
    const int qi   = wave & 1;   // q 16-row half
    const int ni   = wave >> 1;  // score col / O d-col 16-block

    const int qb = blockIdx.x;
    const int h  = blockIdx.y;
    const int b  = blockIdx.z;
    const int bh = b * H_ + h;

    const float* Qg = q + ((size_t)bh * S_ + (size_t)qb * QB) * D_;
    const float* Kg = k + (size_t)bh * S_ * D_;
    const float* Vg = v + (size_t)bh * S_ * D_;
    const int*   Mg = mask + ((size_t)b * S_ + (size_t)qb * QB) * S_;
    float* res_out  = out + ((size_t)bh * S_ + (size_t)qb * QB) * D_;
    float* attn_out = out + (size_t)B_ * H_ * S_ * D_
                          + ((size_t)bh * S_ + (size_t)qb * QB) * S_;

    if (tid < QB) rowred[tid] = 0.f;

    // ---- stage Q (scale 1/8 folded in; exact in fp16: power of 2) ----
    {
        const int row = tid >> 4;
        const int c4  = (tid & 15) * 4;
        const float4 qv = *(const float4*)(Qg + row * D_ + c4);
        f16x4 o;
        o[0] = (f16)(qv.x * 0.125f); o[1] = (f16)(qv.y * 0.125f);
        o[2] = (f16)(qv.z * 0.125f); o[3] = (f16)(qv.w * 0.125f);
        *(f16x4*)&Qsh[row][c4] = o;
    }
    __syncthreads();

    // hoisted A-fragments: A[m=l16][k=quad*8+j], K=64 -> two frags
    const int qrow0 = qi * 16 + quad * 4;
    const f16x8 a0 = *(const f16x8*)&Qsh[qi * 16 + l16][quad * 8];
    const f16x8 a1 = *(const f16x8*)&Qsh[qi * 16 + l16][32 + quad * 8];

    const int colbase = ni * 16 + l16;
    const int* mp0 = Mg + (size_t)qrow0 * S_ + colbase;

    const int skk = tid >> 3;        // staging row (0..63)
    const int sd0 = (tid & 7) * 8;   // staging d-col

    // ================= sweep 1: row sums of exp =================
    float psum[4] = {0.f, 0.f, 0.f, 0.f};
    for (int kt = 0; kt < S_ / KT; ++kt) {
        {
            const float* src = Kg + ((size_t)(kt * KT + skk)) * D_ + sd0;
            const float4 x0 = *(const float4*)(src);
            const float4 x1 = *(const float4*)(src + 4);
            f16x8 o;
            o[0] = (f16)x0.x; o[1] = (f16)x0.y; o[2] = (f16)x0.z; o[3] = (f16)x0.w;
            o[4] = (f16)x1.x; o[5] = (f16)x1.y; o[6] = (f16)x1.z; o[7] = (f16)x1.w;
            *(f16x8*)&Ksh[skk][sd0] = o;
        }
        __syncthreads();
        const f16x8 b0 = *(const f16x8*)&Ksh[ni * 16 + l16][quad * 8];
        const f16x8 b1 = *(const f16x8*)&Ksh[ni * 16 + l16][32 + quad * 8];
        f32x4 c = {0.f, 0.f, 0.f, 0.f};
        c = MFMA16(a0, b0, c);
        c = MFMA16(a1, b1, c);
        const int* mp = mp0 + kt * KT;
#pragma unroll
        for (int r = 0; r < 4; ++r) {
            const int m = mp[(size_t)r * S_];
            const float e = (m == 1) ? 0.f : __expf(c[r]);
            psum[r] += e;
        }
        __syncthreads();
    }

    // reduce psum across the 16 column-lanes of each quad
#pragma unroll
    for (int r = 0; r < 4; ++r) {
        psum[r] += __shfl_xor(psum[r], 1);
        psum[r] += __shfl_xor(psum[r], 2);
        psum[r] += __shfl_xor(psum[r], 4);
        psum[r] += __shfl_xor(psum[r], 8);
    }
    if (l16 == 0) {
#pragma unroll
        for (int r = 0; r < 4; ++r) atomicAdd(&rowred[qrow0 + r], psum[r]);
    }
    __syncthreads();
    if (tid < QB) rlsh[tid] = 1.0f / rowred[tid];
    __syncthreads();
    float rlq[4];
#pragma unroll
    for (int r = 0; r < 4; ++r) rlq[r] = rlsh[qrow0 + r];

    // ================= sweep 2: write attn, accumulate O =================
    f32x4 oacc = {0.f, 0.f, 0.f, 0.f};
    float* ap0 = attn_out + (size_t)qrow0 * S_ + colbase;

    for (int kt = 0; kt < S_ / KT; ++kt) {
        {
            const float* srck = Kg + ((size_t)(kt * KT + skk)) * D_ + sd0;
            const float4 x0 = *(const float4*)(srck);
            const float4 x1 = *(const float4*)(srck + 4);
            f16x8 o;
            o[0] = (f16)x0.x; o[1] = (f16)x0.y; o[2] = (f16)x0.z; o[3] = (f16)x0.w;
            o[4] = (f16)x1.x; o[5] = (f16)x1.y; o[6] = (f16)x1.z; o[7] = (f16)x1.w;
            *(f16x8*)&Ksh[skk][sd0] = o;

            const float* srcv = Vg + ((size_t)(kt * KT + skk)) * D_ + sd0;
            const float4 y0 = *(const float4*)(srcv);
            const float4 y1 = *(const float4*)(srcv + 4);
            f16x2 p01, p23, p45, p67;
            p01[0] = (f16)y0.x; p01[1] = (f16)y0.y;
            p23[0] = (f16)y0.z; p23[1] = (f16)y0.w;
            p45[0] = (f16)y1.x; p45[1] = (f16)y1.y;
            p67[0] = (f16)y1.z; p67[1] = (f16)y1.w;
            *(f16x2*)&Vsh[skk][sd0]     = p01;
            *(f16x2*)&Vsh[skk][sd0 + 2] = p23;
            *(f16x2*)&Vsh[skk][sd0 + 4] = p45;
            *(f16x2*)&Vsh[skk][sd0 + 6] = p67;
        }
        __syncthreads();
        // scores (recompute)
        const f16x8 b0 = *(const f16x8*)&Ksh[ni * 16 + l16][quad * 8];
        const f16x8 b1 = *(const f16x8*)&Ksh[ni * 16 + l16][32 + quad * 8];
        f32x4 c = {0.f, 0.f, 0.f, 0.f};
        c = MFMA16(a0, b0, c);
        c = MFMA16(a1, b1, c);
        const int* mp = mp0 + kt * KT;
        float* ap = ap0 + kt * KT;
#pragma unroll
        for (int r = 0; r < 4; ++r) {
            const int m = mp[(size_t)r * S_];
            const float e = (m == 1) ? 0.f : __expf(c[r]);
            const float p = e * rlq[r];
            ap[(size_t)r * S_] = p;                 // attn output (537 MB total)
            Psh[qrow0 + r][colbase] = (f16)p;       // C-layout -> A-layout via LDS
        }
        __syncthreads();
        // PV: wave tile (qi rows, ni -> d-block)
        const f16x8 pa0 = *(const f16x8*)&Psh[qi * 16 + l16][quad * 8];
        const f16x8 pa1 = *(const f16x8*)&Psh[qi * 16 + l16][32 + quad * 8];
        f16x8 vb0, vb1;
        const int dcol = ni * 16 + l16;
#pragma unroll
        for (int j = 0; j < 8; ++j) {
            vb0[j] = Vsh[quad * 8 + j][dcol];
            vb1[j] = Vsh[32 + quad * 8 + j][dcol];
        }
        oacc = MFMA16(pa0, vb0, oacc);
        oacc = MFMA16(pa1, vb1, oacc);
        __syncthreads();
    }

    // res: rows qrow0+r, col = ni*16+l16 (1/l already folded into P)
#pragma unroll
    for (int r = 0; r < 4; ++r)
        res_out[(size_t)(qrow0 + r) * D_ + ni * 16 + l16] = oacc[r];
}

extern "C" void kernel_launch(void* const* d_in, const int* in_sizes, int n_in,
                              void* d_out, int out_size, void* d_ws, size_t ws_size,
                              hipStream_t stream) {
    (void)in_sizes; (void)n_in; (void)out_size; (void)d_ws; (void)ws_size;
    const float* q   = (const float*)d_in[0];
    const float* k   = (const float*)d_in[1];
    const float* v   = (const float*)d_in[2];
    const int*  mask = (const int*)d_in[3];
    float* out = (float*)d_out;
    dim3 grid(S_ / QB, H_, B_);   // qblock fastest -> K/V L2 reuse; mask from L3
    attn_kernel<<<grid, dim3(NTHREADS), 0, stream>>>(q, k, v, mask, out);
}